// Round 4
// baseline (3827.240 us; speedup 1.0000x reference)
//
#include <hip/hip_runtime.h>
#include <math.h>

// SparseCoding, round 17 = R16 resubmit (container failed twice = infra flake;
// re-audited for deadlock/bounds/resource issues, none found; grid fully
// co-resident at 1 block/CU so the gbar spin cannot deadlock).
// R15 post-mortem: 370 us. VGPR_Count=128 (compiler caps arch VGPRs at 128
// here; demand ~230 -> hot spills, WRITE_SIZE 27-29MB scratch writeback), and
// only 63 blocks x 8 waves (2/SIMD) after Gram -> no latency hiding, plus 4x
// serial setup per block.
// R17: same block-local structure (1 block = 1 window; no per-iter global
// transport) but re-shaped to genuinely fit 128 VGPRs with 4 waves/SIMD:
//  * 1024 threads / 16 waves; each wave owns 16 N-cols. G frags: 8kk x
//    {hi,lo} x 8 bf16 = 64 VGPR (was 128). Per-thread: 8 coefs ->
//    cf/m/v 24 + xB 8 + acc 8 + G 64 + misc ~= 120 < 128. No spills.
//  * MFMA/wave/iter: 64 (4 A-tile ds_read_b128 + 8 MFMA per kk step).
//    A-stack 64x256 bf16 (rows 0-31 coef-hi, 32-63 coef-lo) double-buffered,
//    same XOR swizzle (uniform 8-way granule spread = optimal for b128).
//  * Setup: 1024 threads, per-thread work halved; xB arithmetic BIT-IDENTICAL
//    to R13: wave pair (2u,2u+1) splits each 8-row group (4 rows each), each
//    runs R13's exact contiguous-K=128 fma chains for slice u; slice-gather
//    ascending u unchanged; gathered straight into registers (static index
//    via rg<2 branch - avoids runtime-indexed-array scratch, rule #20).
//  * Loss/convergence machinery identical to R15 (LDS parity ring, lag-2
//    consume by tid64, post-loop round, Adam-undo epilogue), ring width 16.
#define NB     256
#define NF     128
#define FT     1024
#define NW     63
#define TORIG  256
#define RPB    8
#define GRID   256

using f32x4  = __attribute__((ext_vector_type(4))) float;
using bf16x8 = __attribute__((ext_vector_type(8))) short;

// setup xB exchange layout (float4 index): k2*512 + row*64 + (cg ^ row)
__device__ __forceinline__ int xidx(int k2, int cg, int row) {
    return (k2 * 512 + row * 64 + (cg ^ row)) * 4;
}

// round-to-nearest-even fp32 -> bf16 bits (upper 16)
__device__ __forceinline__ unsigned bf16_hi(float x) {
    const unsigned u = __float_as_uint(x);
    return (u + 0x7fffu + ((u >> 16) & 1u)) >> 16;
}

__global__ __launch_bounds__(1024, 4) void window_kernel(
    const float* __restrict__ spec,
    const float* __restrict__ basis,
    float* __restrict__ G,               // ws: 256x256
    const int* __restrict__ p_niter,
    const int* __restrict__ p_pad,
    const int* __restrict__ p_stride,
    unsigned int* __restrict__ gbar,     // single word, memset 0
    float* __restrict__ out)             // (32,256,63)
{
    // arena: setup = s_p0 (64KB xB exchange); loop = A0 @0 / A1 @32768 (bytes)
    __shared__ __align__(16) char arena[65536];
    float* const s_p0 = (float*)arena;
    __shared__ __align__(16) float s_xn[RPB * FT];   // 32KB staging (per group)
    __shared__ float  s_gred[4][NB];
    __shared__ float  s_mn[RPB], s_rng[RPB];
    __shared__ double s_dred[16];
    __shared__ double s_sx;
    __shared__ float  s_redq[2][16], s_redr[2][16];
    __shared__ int    s_stop[2];

    const int bid = blockIdx.x;
    const int tid = threadIdx.x;
    const int ks  = tid >> 6;                    // wave 0..15
    const int kg  = tid & 63;
    const int lr  = kg & 15;                     // C col within 16-tile
    const int lh  = kg >> 4;                     // lane group 0..3
    const int n_iter = p_niter[0];

    // ================= fused Gram: block bid computes G row bid ==================
    {
        const int c = tid & 255, jh = tid >> 8;  // 4 j-quarters
        float acc = 0.f;
        const float* bp = basis + (size_t)(jh * 256) * NB;
        #pragma unroll 16
        for (int j = 0; j < 256; ++j)
            acc = fmaf(bp[j * NB + bid], bp[j * NB + c], acc);
        s_gred[jh][c] = acc;
        __syncthreads();
        if (jh == 0)
            G[(size_t)bid * NB + c] =
                s_gred[0][c] + s_gred[1][c] + s_gred[2][c] + s_gred[3][c];
    }
    __threadfence();
    __syncthreads();
    if (tid == 0) atomicAdd(gbar, 1u);
    if (bid >= NW) return;                       // 193 blocks exit after Gram

    const int w  = bid;
    const int t0 = w * p_stride[0] - p_pad[0];
    if (tid == 0) s_sx = 0.0;

    const int cc = 16 * ks + lr;                 // owned column (loop phase)
    float xB[8];

    // ======== setup per 8-row group: stage, normalize, xB (R13 arithmetic) ======
    #pragma unroll 1
    for (int rg = 0; rg < 4; ++rg) {
        #pragma unroll
        for (int i = 0; i < 8; ++i) {
            const int e = i * 1024 + tid;
            const int b = e >> 10, jj = e & 1023;
            const int f = jj >> 3, t = jj & 7, tq = t0 + t;
            s_xn[b * FT + jj] = (tq >= 0 && tq < TORIG)
                ? spec[((size_t)(rg * RPB + b) * NF + f) * TORIG + tq] : 0.f;
        }
        __syncthreads();
        if (ks < 8) {   // wave ks scans row ks
            float mn = __builtin_inff(), mx = -__builtin_inff();
            #pragma unroll
            for (int i = 0; i < 16; ++i) {
                const float v = s_xn[ks * FT + i * 64 + kg];
                mn = fminf(mn, v); mx = fmaxf(mx, v);
            }
            #pragma unroll
            for (int off = 32; off; off >>= 1) {
                mn = fminf(mn, __shfl_down(mn, off));
                mx = fmaxf(mx, __shfl_down(mx, off));
            }
            if (kg == 0) { s_mn[ks] = mn; s_rng[ks] = mx - mn; }
        }
        __syncthreads();
        double sx2p = 0.0;
        #pragma unroll
        for (int i = 0; i < 8; ++i) {
            const int e = i * 1024 + tid;
            const int b = e >> 10, jj = e & 1023;
            const float v = (s_xn[b * FT + jj] - s_mn[b]) / s_rng[b];
            s_xn[b * FT + jj] = v;
            sx2p += (double)v * (double)v;
        }
        #pragma unroll
        for (int off = 32; off; off >>= 1) sx2p += __shfl_down(sx2p, off);
        if (kg == 0) s_dred[ks] = sx2p;
        __syncthreads();
        if (tid == 0) {
            double s = 0.0;
            #pragma unroll
            for (int i = 0; i < 16; ++i) s += s_dred[i];
            s_sx += s;
        }

        // xB partials: wave pair (2u, 2u+1) = K-slice u, rows 4*(ks&1)..+4.
        // Per-row fma chains are bit-identical to R13's wave-u chains.
        const int u = ks >> 1, hf2 = ks & 1;
        float xbp[4][4];
        #pragma unroll
        for (int b = 0; b < 4; ++b)
            #pragma unroll
            for (int j = 0; j < 4; ++j) xbp[b][j] = 0.f;
        for (int i0 = 0; i0 < 128; i0 += 4) {
            const int jj = u * 128 + i0;
            float4 bv[4];
            #pragma unroll
            for (int t = 0; t < 4; ++t)
                bv[t] = *(const float4*)(basis + (size_t)(jj + t) * NB + 4 * kg);
            #pragma unroll
            for (int b = 0; b < 4; ++b) {
                const float4 x4 = *(const float4*)&s_xn[(4 * hf2 + b) * FT + jj];
                xbp[b][0] = fmaf(x4.x, bv[0].x, fmaf(x4.y, bv[1].x, fmaf(x4.z, bv[2].x, fmaf(x4.w, bv[3].x, xbp[b][0]))));
                xbp[b][1] = fmaf(x4.x, bv[0].y, fmaf(x4.y, bv[1].y, fmaf(x4.z, bv[2].y, fmaf(x4.w, bv[3].y, xbp[b][1]))));
                xbp[b][2] = fmaf(x4.x, bv[0].z, fmaf(x4.y, bv[1].z, fmaf(x4.z, bv[2].z, fmaf(x4.w, bv[3].z, xbp[b][2]))));
                xbp[b][3] = fmaf(x4.x, bv[0].w, fmaf(x4.y, bv[1].w, fmaf(x4.z, bv[2].w, fmaf(x4.w, bv[3].w, xbp[b][3]))));
            }
        }
        #pragma unroll
        for (int b = 0; b < 4; ++b)
            *(float4*)&s_p0[xidx(u, kg, 4 * hf2 + b)] =
                make_float4(xbp[b][0], xbp[b][1], xbp[b][2], xbp[b][3]);
        __syncthreads();
        // gather owned coefs whose rows fall in this group (ascending u = R13
        // order); static destination index via rg<2 branch.
        if ((lh >> 1) == (rg & 1)) {
            float vv[4];
            #pragma unroll
            for (int t = 0; t < 4; ++t) {
                const int r8 = 4 * (lh & 1) + t;
                float s = 0.f;
                #pragma unroll
                for (int u2 = 0; u2 < 8; ++u2)
                    s += s_p0[xidx(u2, cc >> 2, r8) + (cc & 3)];
                vv[t] = s;
            }
            if (rg < 2) { xB[0] = vv[0]; xB[1] = vv[1]; xB[2] = vv[2]; xB[3] = vv[3]; }
            else        { xB[4] = vv[0]; xB[5] = vv[1]; xB[6] = vv[2]; xB[7] = vv[3]; }
        }
    }

    // ================= wait for G; init block-local state ========================
    if (tid == 0) {
        while (__hip_atomic_load(gbar, __ATOMIC_ACQUIRE, __HIP_MEMORY_SCOPE_AGENT) < (unsigned)GRID)
            __builtin_amdgcn_s_sleep(1);
    }
    if (tid == 64) { s_stop[0] = 0; s_stop[1] = 0; }
    __syncthreads();   // all gathers done -> arena reusable as A0/A1

    // G B-fragments (wave's 16 cols, full K), hi/lo bf16 split.
    // B layout: col = lane&15, k = 8*(lane>>4) + b + 32*kk.
    bf16x8 Gh[8], Gl[8];
    {
        const float* gp = G + (size_t)(8 * lh) * NB + cc;
        #pragma unroll
        for (int kk = 0; kk < 8; ++kk)
            #pragma unroll
            for (int b = 0; b < 8; ++b) {
                const float gv = gp[(size_t)(32 * kk + b) * NB];
                const unsigned hb = bf16_hi(gv);
                const float    hf = __uint_as_float(hb << 16);
                Gh[kk][b] = (short)hb;
                Gl[kk][b] = (short)bf16_hi(gv - hf);
            }
    }

    // A tile: 64x256 bf16 (rows 0-31 hi, 32-63 lo); swizzle short-idx ^= (row&7)<<3.
    const int ro  = lr * 256 + 8 * lh;           // read base (shorts), Mtile 0
    const int swz = (lr & 7) << 3;

    // ================= init owned coef / Adam; write A0 ==========================
    const float C0 = 0.5f / 256.f;
    float cf[8], m_[8], v_[8];
    #pragma unroll
    for (int j = 0; j < 8; ++j) { cf[j] = C0; m_[j] = 0.f; v_[j] = 0.f; }
    {
        const short vh = (short)bf16_hi(C0);     // C0 = 2^-9 exact, lo = 0
        #pragma unroll
        for (int pp = 0; pp < 2; ++pp)
            #pragma unroll
            for (int t = 0; t < 4; ++t) {
                const int rr = 16 * pp + 4 * lh + t;
                const int wb = ((rr * 256 + cc) ^ ((rr & 7) << 3)) << 1;
                *(short*)(arena + wb)         = vh;   // hi row
                *(short*)(arena + wb + 16384) = 0;    // lo row (+32 rows)
            }
    }
    float b1p = 1.f, b2p = 1.f;
    float old_loss = 1e-10f;      // tid64 only
    double sxtot = 0.0;           // tid64 only
    const float c1c = 2.f / 32768.f, c2c = 0.2f / 8192.f;
    int use_prev = 0;

    for (int it = 0; it < n_iter; ++it) {
        const int p = it & 1;
        const char* rdb = arena + (p ? 32768 : 0);
        char*       wrb = arena + (p ? 0 : 32768);

        __syncthreads();          // barrier 1: A[rdb] writes (prev iter) visible

        // ---- MFMA: (Ahi+Alo) @ (Ghi+Glo); acc0 = coef rows 0-15, acc1 = 16-31 ----
        f32x4 acc0 = {0.f, 0.f, 0.f, 0.f}, acc1 = {0.f, 0.f, 0.f, 0.f};
        #pragma unroll 2
        for (int kk = 0; kk < 8; ++kk) {
            const int o = ro + 32 * kk;
            const bf16x8 ah0 = *(const bf16x8*)(rdb + (((o        ) ^ swz) << 1));
            const bf16x8 ah1 = *(const bf16x8*)(rdb + (((o +  4096) ^ swz) << 1));
            const bf16x8 al0 = *(const bf16x8*)(rdb + (((o +  8192) ^ swz) << 1));
            const bf16x8 al1 = *(const bf16x8*)(rdb + (((o + 12288) ^ swz) << 1));
            acc0 = __builtin_amdgcn_mfma_f32_16x16x32_bf16(ah0, Gh[kk], acc0, 0, 0, 0);
            acc0 = __builtin_amdgcn_mfma_f32_16x16x32_bf16(al0, Gh[kk], acc0, 0, 0, 0);
            acc0 = __builtin_amdgcn_mfma_f32_16x16x32_bf16(ah0, Gl[kk], acc0, 0, 0, 0);
            acc0 = __builtin_amdgcn_mfma_f32_16x16x32_bf16(al0, Gl[kk], acc0, 0, 0, 0);
            acc1 = __builtin_amdgcn_mfma_f32_16x16x32_bf16(ah1, Gh[kk], acc1, 0, 0, 0);
            acc1 = __builtin_amdgcn_mfma_f32_16x16x32_bf16(al1, Gh[kk], acc1, 0, 0, 0);
            acc1 = __builtin_amdgcn_mfma_f32_16x16x32_bf16(ah1, Gl[kk], acc1, 0, 0, 0);
            acc1 = __builtin_amdgcn_mfma_f32_16x16x32_bf16(al1, Gl[kk], acc1, 0, 0, 0);
        }

        // ---- tid64: LAG-2 consume, LDS-local (parity ring = lag-2 store) ----
        if (tid == 64 && it >= 2) {
            const int itc = it - 2;
            double Qt = 0.0, Rt = 0.0;
            #pragma unroll
            for (int i = 0; i < 16; ++i) {
                Qt += (double)s_redq[p][i];
                Rt += (double)s_redr[p][i];
            }
            if (itc == 0) sxtot = s_sx;
            const float loss = (float)((Qt + sxtot) / 32768.0 + 0.2 * (Rt / 8192.0));
            const float stat = fabsf(old_loss - loss) / old_loss;
            old_loss = loss;
            s_stop[p] = (stat < 1e-3f) ? 1 : 0;
        }

        __syncthreads();          // barrier 2: s_stop[p] + ring consume done

        if (s_stop[p]) { use_prev = 1; break; }

        // ---- loss partials -> parity ring (block-local) ----
        if (it + 1 < n_iter) {
            float qc = 0.f, rr_ = 0.f;
            #pragma unroll
            for (int j = 0; j < 8; ++j) {
                const float a4v = (j < 4) ? acc0[j] : acc1[j - 4];
                qc += cf[j] * (a4v - 2.f * xB[j]);
                rr_ += fabsf(cf[j]);
            }
            #pragma unroll
            for (int off = 32; off; off >>= 1) {
                qc  += __shfl_down(qc, off);
                rr_ += __shfl_down(rr_, off);
            }
            if (kg == 0) { s_redq[p][ks] = qc; s_redr[p][ks] = rr_; }
        }

        // ---- Adam update (fast rcp/sqrt) ----
        b1p *= 0.9f; b2p *= 0.999f;
        const float rb1 = __builtin_amdgcn_rcpf(1.f - b1p);
        const float rb2 = __builtin_amdgcn_rcpf(1.f - b2p);
        #pragma unroll
        for (int j = 0; j < 8; ++j) {
            const float a4v = (j < 4) ? acc0[j] : acc1[j - 4];
            const float c_  = cf[j];
            const float sgn = (c_ > 0.f) ? 1.f : ((c_ < 0.f) ? -1.f : 0.f);
            const float gg  = c1c * (a4v - xB[j]) + c2c * sgn;
            m_[j] = 0.9f * m_[j] + 0.1f * gg;
            v_[j] = 0.999f * v_[j] + 0.001f * gg * gg;
            const float den = __builtin_amdgcn_sqrtf(v_[j] * rb2) + 1e-8f;
            cf[j] = c_ - 1e-3f * (m_[j] * rb1) * __builtin_amdgcn_rcpf(den);
        }

        // ---- bf16 hi/lo split of new coef -> next A buffer ----
        #pragma unroll
        for (int pp = 0; pp < 2; ++pp)
            #pragma unroll
            for (int t = 0; t < 4; ++t) {
                const int j  = pp * 4 + t;
                const int rr = 16 * pp + 4 * lh + t;
                const int wb = ((rr * 256 + cc) ^ ((rr & 7) << 3)) << 1;
                const unsigned hb = bf16_hi(cf[j]);
                const float    hf = __uint_as_float(hb << 16);
                *(short*)(wrb + wb)         = (short)hb;
                *(short*)(wrb + wb + 16384) = (short)bf16_hi(cf[j] - hf);
            }
    }

    // ---- post-loop consume round: conv at t = n_iter-2 (if not already stopped) ----
    if (!use_prev && n_iter >= 2) {
        if (tid == 64) {
            const int itc = n_iter - 2;
            const int pc  = itc & 1;
            double Qt = 0.0, Rt = 0.0;
            #pragma unroll
            for (int i = 0; i < 16; ++i) {
                Qt += (double)s_redq[pc][i];
                Rt += (double)s_redr[pc][i];
            }
            if (itc == 0) sxtot = s_sx;
            const float loss = (float)((Qt + sxtot) / 32768.0 + 0.2 * (Rt / 8192.0));
            const float stat = fabsf(old_loss - loss) / old_loss;
            s_stop[0] = (stat < 1e-3f) ? 1 : 0;
        }
        __syncthreads();
        use_prev = s_stop[0];
    }

    // ---- output; on stop reconstruct pre-step coef by exact Adam-step undo ----
    {
        const float rb1e = __builtin_amdgcn_rcpf(1.f - b1p);
        const float rb2e = __builtin_amdgcn_rcpf(1.f - b2p);
        #pragma unroll
        for (int pp = 0; pp < 2; ++pp)
            #pragma unroll
            for (int t = 0; t < 4; ++t) {
                const int j = pp * 4 + t;
                float val = cf[j];
                if (use_prev) {
                    const float den = __builtin_amdgcn_sqrtf(v_[j] * rb2e) + 1e-8f;
                    val += 1e-3f * (m_[j] * rb1e) * __builtin_amdgcn_rcpf(den);
                }
                out[((size_t)(16 * pp + 4 * lh + t) * NB + cc) * NW + w] = val;
            }
    }
}

// ---------------------------------------------------------------------------
extern "C" void kernel_launch(void* const* d_in, const int* in_sizes, int n_in,
                              void* d_out, int out_size, void* d_ws, size_t ws_size,
                              hipStream_t stream)
{
    const float* spec   = (const float*)d_in[0];
    const float* basis  = (const float*)d_in[1];
    const int* p_niter  = (const int*)d_in[2];
    const int* p_pad    = (const int*)d_in[3];
    const int* p_stride = (const int*)d_in[4];
    float* out = (float*)d_out;

    char* ws = (char*)d_ws;
    float*        G    = (float*)ws;                 // 256 KB
    unsigned int* gbar = (unsigned int*)(ws + 262144);

    hipMemsetAsync(gbar, 0, sizeof(unsigned int), stream);
    window_kernel<<<dim3(GRID), dim3(1024), 0, stream>>>(
        spec, basis, G, p_niter, p_pad, p_stride, gbar, out);
}